// Round 5
// baseline (1551.238 us; speedup 1.0000x reference)
//
#include <hip/hip_runtime.h>
#include <hip/hip_bf16.h>
#include <hip/hip_fp16.h>
#include <math.h>

#define N_NODES 65536
#define N_GRAPH 256
#define P_NODES 256
#define N_EDGES 1048576
#define AF 92
#define BF 41
#define DIM 64
#define HID 128
#define NLAYER 3
#define CE 16
#define TS 4
#define BN_EPS 1e-5f
#define PSTRIDE 33    // padded edge-dim stride of LDS panel in k_e0m

typedef _Float16 half8 __attribute__((ext_vector_type(8)));
typedef float floatx4 __attribute__((ext_vector_type(4)));
typedef float floatx16 __attribute__((ext_vector_type(16)));

// fast softplus: native v_exp/v_log, abs err ~1e-7 (budget 2e-2)
__device__ __forceinline__ float softplus_f(float x) {
    return fmaxf(x, 0.0f) + __logf(1.0f + __expf(-fabsf(x)));
}

// pack two floats to 2xfp16 in an int (via documented HIP API; compiles to cvt+pack)
__device__ __forceinline__ int pkcvt(float a, float b) {
    __half2 h = __floats2half2_rn(a, b);
    int r; __builtin_memcpy(&r, &h, 4); return r;
}

__device__ __forceinline__ half8 mk8(int a, int b, int c, int d) {
    union { half8 v; int i[4]; } u;
    u.i[0] = a; u.i[1] = b; u.i[2] = c; u.i[3] = d;
    return u.v;
}

__device__ __forceinline__ floatx16 mfma32(half8 a, half8 b, floatx16 c) {
    return __builtin_amdgcn_mfma_f32_32x32x16_f16(a, b, c, 0, 0, 0);
}

// C-frag (32x32: col=lane&31=edge, row=(reg&3)+8*(reg>>2)+4*(lane>>5)) ->
// B-frag of next GEMM (col=lane&31, k=(lane>>5)*8+j) for kstep pair s_local.
// Own-half supplies 4 of the 8 k's; the other 4 come via lane^32 exchange.
__device__ __forceinline__ half8 chain_frag(const floatx16& t, int s_local, bool hi) {
    const int rA = 8 * s_local;       // reg base of row-group 2*s_local
    const int rB = rA + 4;            // reg base of row-group 2*s_local+1
    int A0 = pkcvt(t[rA + 0], t[rA + 1]);
    int A1 = pkcvt(t[rA + 2], t[rA + 3]);
    int B0 = pkcvt(t[rB + 0], t[rB + 1]);
    int B1 = pkcvt(t[rB + 2], t[rB + 3]);
    int S0 = hi ? A0 : B0, S1 = hi ? A1 : B1;   // lo sends B-group, hi sends A-group
    int R0 = __shfl_xor(S0, 32), R1 = __shfl_xor(S1, 32);
    int w0 = hi ? R0 : A0, w1 = hi ? R1 : A1;
    int w2 = hi ? B0 : R0, w3 = hi ? B1 : R1;
    return mk8(w0, w1, w2, w3);
}

// ---------------------------------------------------------------- initial h
__global__ __launch_bounds__(64) void k_h0(
    const float* __restrict__ x, const float* __restrict__ charge,
    const float* __restrict__ chW, const float* __restrict__ chb,
    const float* __restrict__ atomW, const float* __restrict__ atomb,
    const int* __restrict__ batch, float* __restrict__ h,
    __half* __restrict__ h16)
{
    const int n = blockIdx.x * 64 + threadIdx.x;
    float acc[DIM];
#pragma unroll
    for (int j = 0; j < DIM; ++j) acc[j] = atomb[j];
    const float* xr = x + (size_t)n * AF;
    for (int k2 = 0; k2 < AF; k2 += 2) {
        float2 a = *(const float2*)(xr + k2);
        {
            const float* w = atomW + (size_t)k2 * DIM;
#pragma unroll
            for (int j = 0; j < DIM; ++j) acc[j] = fmaf(w[j], a.x, acc[j]);
        }
        {
            const float* w = atomW + (size_t)(k2 + 1) * DIM;
#pragma unroll
            for (int j = 0; j < DIM; ++j) acc[j] = fmaf(w[j], a.y, acc[j]);
        }
    }
    const float cg = charge[batch[n]];
#pragma unroll
    for (int k = 0; k < CE; ++k) {
        float av = fmaf(cg, chW[k], chb[k]);
        const float* w = atomW + (size_t)(AF + k) * DIM;
#pragma unroll
        for (int j = 0; j < DIM; ++j) acc[j] = fmaf(w[j], av, acc[j]);
    }
    float* hp = h + (size_t)n * DIM;
    _Float16* hq = (_Float16*)h16 + (size_t)n * DIM;
#pragma unroll
    for (int j = 0; j < DIM; j += 4)
        *(float4*)(hp + j) = make_float4(acc[j], acc[j+1], acc[j+2], acc[j+3]);
#pragma unroll
    for (int j = 0; j < DIM; j += 8) {
        half8 hv;
#pragma unroll
        for (int u = 0; u < 8; ++u) hv[u] = (_Float16)acc[j + u];
        *(half8*)(hq + j) = hv;
    }
}

// ---------------------------------------------------------------- CSR build
__global__ __launch_bounds__(256) void k_hist(const int* __restrict__ ecol,
                                              int* __restrict__ cnt)
{
    int t = blockIdx.x * 256 + threadIdx.x;
    atomicAdd(&cnt[ecol[t]], 1);
}

__global__ __launch_bounds__(256) void k_blksum(const int* __restrict__ cnt,
                                                int* __restrict__ bs)
{
    __shared__ int red[256];
    red[threadIdx.x] = cnt[blockIdx.x * 256 + threadIdx.x];
    __syncthreads();
    for (int o = 128; o > 0; o >>= 1) {
        if (threadIdx.x < o) red[threadIdx.x] += red[threadIdx.x + o];
        __syncthreads();
    }
    if (threadIdx.x == 0) bs[blockIdx.x] = red[0];
}

__global__ __launch_bounds__(256) void k_scanb(const int* __restrict__ bs,
                                               int* __restrict__ bo)
{
    __shared__ int ps[256];
    const int t = threadIdx.x;
    int v = bs[t];
    ps[t] = v;
    __syncthreads();
    for (int off = 1; off < 256; off <<= 1) {
        int u = (t >= off) ? ps[t - off] : 0;
        __syncthreads();
        ps[t] += u;
        __syncthreads();
    }
    bo[t] = ps[t] - v;   // exclusive
}

__global__ __launch_bounds__(256) void k_scan3(const int* __restrict__ cnt,
                                               const int* __restrict__ bo,
                                               int* __restrict__ starts)
{
    __shared__ int ps[256];
    const int b = blockIdx.x, t = threadIdx.x;
    int v = cnt[b * 256 + t];
    ps[t] = v;
    __syncthreads();
    for (int off = 1; off < 256; off <<= 1) {
        int u = (t >= off) ? ps[t - off] : 0;
        __syncthreads();
        ps[t] += u;
        __syncthreads();
    }
    starts[b * 256 + t] = bo[b] + ps[t] - v;
    if (b == 255 && t == 255) starts[N_NODES] = bo[255] + ps[255];
}

__global__ __launch_bounds__(256) void k_scatter(const int* __restrict__ ecol,
                                                 int* __restrict__ cur,
                                                 int* __restrict__ perm,
                                                 int* __restrict__ ipos)
{
    int t = blockIdx.x * 256 + threadIdx.x;
    int pos = atomicAdd(&cur[ecol[t]], 1);
    perm[pos] = t;
    ipos[t] = pos;
}

// ------------- bondW [41x64] -> fp16 B-frag (16x16x32 layout) for k_e0m
__global__ __launch_bounds__(256) void k_wprep_bond(
    const float* __restrict__ bondW, __half* __restrict__ out)
{
    const int idx = blockIdx.x * 256 + threadIdx.x;   // 4096 threads
    int j    = idx & 7;
    int lane = (idx >> 3) & 63;
    int f    = idx >> 9;
    int ntile = f & 3;
    int kIter = f >> 2;
    int k = kIter * 32 + ((lane >> 4) & 3) * 8 + j;
    int n = ntile * 16 + (lane & 15);
    out[idx] = (k < BF) ? __float2half(bondW[k * 64 + n]) : __float2half(0.0f);
}

// fused weight: W' = euW2 @ nuW1_bot  [64x64], b' = eub2 @ nuW1_bot + nub1.
__global__ __launch_bounds__(64) void k_wfuse(
    const float* __restrict__ euW2, const float* __restrict__ nuW1,
    const float* __restrict__ eub2, const float* __restrict__ nub1,
    float* __restrict__ WfuF32, float* __restrict__ bfu)
{
    const int L = blockIdx.x, j = threadIdx.x;
    const float* W2  = euW2 + (size_t)L * DIM * DIM;             // [k][l]
    const float* N1b = nuW1 + (size_t)L * 128 * DIM + 64 * DIM;  // [l][j]
    float acc[64];
#pragma unroll
    for (int k = 0; k < 64; ++k) acc[k] = 0.f;
    for (int l = 0; l < 64; ++l) {
        float nv = N1b[l * 64 + j];
#pragma unroll
        for (int k = 0; k < 64; ++k) acc[k] = fmaf(W2[k * 64 + l], nv, acc[k]);
    }
    float* outW = WfuF32 + (size_t)L * 4096;
    for (int k = 0; k < 64; ++k) outW[k * 64 + j] = acc[k];
    float b = nub1[L * 64 + j];
    for (int l = 0; l < 64; ++l) b = fmaf(eub2[L * 64 + l], N1b[l * 64 + j], b);
    bfu[L * 64 + j] = b;
}

// -------- A-frag prepack for k_edge5 (32x32x16: row=l&31, k=(l>>5)*8+j).
// Per layer, 64 frags of 1KB (64 lanes x half8):
//  F  0..25 : G1  euW1^T (+eub1 at k=192)   mt*13+ks, K=13 ksteps
//  F 26..35 : G2  euW2^T (+eub2 at k=64)    26+mt*5+ks
//  F 36..43 : G3a nuW1_top^T (no bias)      36+mt*4+ks
//  F 44..53 : G3b W'^T (+b' at k=64)        44+mt*5+ks
//  F 54..63 : G4  nuW2^T (+nub2 at k=64)    54+mt*5+ks
__global__ __launch_bounds__(256) void k_wprepB(
    const float* __restrict__ euW1, const float* __restrict__ eub1,
    const float* __restrict__ euW2, const float* __restrict__ eub2,
    const float* __restrict__ nuW1, const float* __restrict__ WfuF32,
    const float* __restrict__ bfu,  const float* __restrict__ nuW2,
    const float* __restrict__ nub2, __half* __restrict__ out)
{
    const int idx = blockIdx.x * 256 + threadIdx.x;   // 3*32768 threads
    const int L = idx >> 15;
    const int off = idx & 32767;
    const int F = off >> 9;
    const int l = (off >> 3) & 63;
    const int j = off & 7;
    const int k_oct = ((l >> 5) << 3) + j;
    const int row = (l & 31);
    float val;
    if (F < 26) {
        int mt = F / 13, ks = F - mt * 13;
        int k = ks * 16 + k_oct, r = mt * 32 + row;
        val = (k < 192) ? euW1[(size_t)L * 192 * DIM + k * 64 + r]
            : (k == 192 ? eub1[L * 64 + r] : 0.f);
    } else if (F < 36) {
        int f = F - 26; int mt = f / 5, ks = f - mt * 5;
        int k = ks * 16 + k_oct, r = mt * 32 + row;
        val = (k < 64) ? euW2[(size_t)L * 4096 + k * 64 + r]
            : (k == 64 ? eub2[L * 64 + r] : 0.f);
    } else if (F < 44) {
        int f = F - 36; int mt = f / 4, ks = f - mt * 4;
        int k = ks * 16 + k_oct, r = mt * 32 + row;
        val = nuW1[(size_t)L * 8192 + k * 64 + r];
    } else if (F < 54) {
        int f = F - 44; int mt = f / 5, ks = f - mt * 5;
        int k = ks * 16 + k_oct, r = mt * 32 + row;
        val = (k < 64) ? WfuF32[(size_t)L * 4096 + k * 64 + r]
            : (k == 64 ? bfu[L * 64 + r] : 0.f);
    } else {
        int f = F - 54; int mt = f / 5, ks = f - mt * 5;
        int k = ks * 16 + k_oct, r = mt * 32 + row;
        val = (k < 64) ? nuW2[(size_t)L * 4096 + k * 64 + r]
            : (k == 64 ? nub2[L * 64 + r] : 0.f);
    }
    out[idx] = __float2half(val);
}

// ---------------- 16x16x32 helpers (used by k_e0m only)
__device__ __forceinline__ void init_acc(floatx4 acc[2][4],
                                         const float* __restrict__ b, int mrow)
{
#pragma unroll
    for (int n = 0; n < 4; ++n) {
        float bv = b[n * 16 + mrow];
        floatx4 f = {bv, bv, bv, bv};
        acc[0][n] = f;
        acc[1][n] = f;
    }
}

__device__ __forceinline__ void gemm_panel(floatx4 acc[2][4],
                                           const _Float16* __restrict__ P,
                                           const __half* __restrict__ Wf,
                                           int fragBase, int quad,
                                           int mrow, int lane)
{
    const _Float16* Wh = (const _Float16*)Wf;
#pragma unroll
    for (int ki = 0; ki < 2; ++ki) {
        const _Float16* pa = P + (size_t)(((ki * 4 + quad) * PSTRIDE + mrow) * 8);
        half8 a0 = *(const half8*)pa;
        half8 a1 = *(const half8*)(pa + 16 * 8);
#pragma unroll
        for (int n = 0; n < 4; ++n) {
            half8 b = *(const half8*)(Wh +
                ((size_t)(fragBase + ki * 4 + n) * 64 + lane) * 8);
            acc[0][n] = __builtin_amdgcn_mfma_f32_16x16x32_f16(a0, b, acc[0][n], 0, 0, 0);
            acc[1][n] = __builtin_amdgcn_mfma_f32_16x16x32_f16(a1, b, acc[1][n], 0, 0, 0);
        }
    }
}

__device__ __forceinline__ void cstore_panel(const floatx4 acc[2][4],
                                             _Float16* __restrict__ P,
                                             int quad, int mrow, bool sp)
{
#pragma unroll
    for (int t = 0; t < 2; ++t)
#pragma unroll
        for (int n = 0; n < 4; ++n)
#pragma unroll
            for (int r = 0; r < 4; ++r) {
                int edge = t * 16 + quad * 4 + r;
                int d = n * 16 + mrow;
                float v = acc[t][n][r];
                if (sp) v = softplus_f(v);
                P[((d >> 3) * PSTRIDE + edge) * 8 + (d & 7)] = (_Float16)v;
            }
}

// ---- initial e as MFMA GEMM: eT[slot] = eattr[E,41] @ bondW[41,64] + bondb.
__device__ __forceinline__ void stage_e2(_Float16* __restrict__ P,
                                         int id2, float2 v)
{
    int idx = id2 * 2;
    int e = (idx * 51151) >> 21;          // floor(idx/41), exact for idx<2^15
    int k = idx - e * 41;
    P[((k >> 3) * PSTRIDE + e) * 8 + (k & 7)] = (_Float16)v.x;
    idx++;
    e = (idx * 51151) >> 21;
    k = idx - e * 41;
    P[((k >> 3) * PSTRIDE + e) * 8 + (k & 7)] = (_Float16)v.y;
}

__global__ __launch_bounds__(64) void k_e0m(
    const float* __restrict__ eattr, const __half* __restrict__ Wb,
    const float* __restrict__ bondb, const int* __restrict__ ipos,
    __half* __restrict__ eT)
{
    __shared__ __align__(16) _Float16 P0[8 * PSTRIDE * 8];
    __shared__ int slot[32];
    const int lane = threadIdx.x;
    const int quad = lane >> 4;
    const int mrow = lane & 15;
    const int e0   = blockIdx.x * 32;

    if (lane < 32) slot[lane] = ipos[e0 + lane];

    {
        half8 z = {};
#pragma unroll
        for (int i = 0; i < 4; ++i) ((half8*)P0)[i * 64 + lane] = z;
        if (lane < 8) ((half8*)P0)[256 + lane] = z;
    }
    __syncthreads();

    const float* src = eattr + (size_t)e0 * BF;
#pragma unroll
    for (int i = 0; i < 10; ++i) {
        const int id2 = i * 64 + lane;
        float2 v = *(const float2*)(src + id2 * 2);
        stage_e2(P0, id2, v);
    }
    if (lane < 16) {
        const int id2 = 640 + lane;
        float2 v = *(const float2*)(src + id2 * 2);
        stage_e2(P0, id2, v);
    }
    __syncthreads();

    floatx4 acc[2][4];
    init_acc(acc, bondb, mrow);
    gemm_panel(acc, P0, Wb, 0, quad, mrow, lane);
    __syncthreads();
    cstore_panel(acc, P0, quad, mrow, false);
    __syncthreads();

#pragma unroll
    for (int i = 0; i < 4; ++i) {
        int idx = i * 64 + lane;
        int eL = idx >> 3;
        int c  = idx & 7;
        half8 v = *(const half8*)&P0[(c * PSTRIDE + eL) * 8];
        *(half8*)((_Float16*)eT + (size_t)slot[eL] * DIM + c * 8) = v;
    }
}

// ---------------------------------------------------------------- edge MLP
// One wave / 32 edges. Swapped-operand 32x32x16 MFMA: M=d_out (2 tiles),
// N=edges(32), activations ride as B-frags straight from global rows; the
// entire 4-GEMM chain stays in registers (no LDS, no barriers). Biases are
// folded into K as an extra kstep against a constant "ones" B-frag.
__global__ __launch_bounds__(64) void k_edge5(
    const __half* __restrict__ h16, __half* __restrict__ eT,
    const __half* __restrict__ WB,
    const int* __restrict__ erow, const int* __restrict__ ecol,
    const int* __restrict__ perm, __half* __restrict__ m)
{
    const int lane = threadIdx.x;
    const int e = lane & 31;
    const bool hi = lane >= 32;
    const int h = hi ? 1 : 0;
    const int e0 = blockIdx.x * 32;
    const int ed = perm[e0 + e];
    const int rs = erow[ed], cs = ecol[ed];

    const half8* WBv = (const half8*)WB;

    half8 fs[4], fd[4], fe[4];
    {
        const _Float16* ps = (const _Float16*)h16 + (size_t)rs * DIM + h * 8;
        const _Float16* pd = (const _Float16*)h16 + (size_t)cs * DIM + h * 8;
        const _Float16* pe = (const _Float16*)eT  + (size_t)(e0 + e) * DIM + h * 8;
#pragma unroll
        for (int s = 0; s < 4; ++s) {
            fs[s] = *(const half8*)(ps + 16 * s);
            fd[s] = *(const half8*)(pd + 16 * s);
            fe[s] = *(const half8*)(pe + 16 * s);
        }
    }
    half8 ones = {};
    if (!hi) ones[0] = (_Float16)1.0f;   // k_local==0 row only

    // ---- GEMM1: t1^T = euW1^T @ [hs|hd|e]^T (+eub1)
    floatx16 t1a = {};
    floatx16 t1b = {};
#pragma unroll
    for (int ks = 0; ks < 13; ++ks) {
        half8 b;
        if (ks < 4)       b = fs[ks & 3];
        else if (ks < 8)  b = fd[(ks - 4) & 3];
        else if (ks < 12) b = fe[(ks - 8) & 3];
        else              b = ones;
        t1a = mfma32(WBv[(0 * 13 + ks) * 64 + lane], b, t1a);
        t1b = mfma32(WBv[(1 * 13 + ks) * 64 + lane], b, t1b);
    }
#pragma unroll
    for (int i = 0; i < 16; ++i) {
        t1a[i] = softplus_f(t1a[i]);
        t1b[i] = softplus_f(t1b[i]);
    }
    half8 bf1[4];
    bf1[0] = chain_frag(t1a, 0, hi);
    bf1[1] = chain_frag(t1a, 1, hi);
    bf1[2] = chain_frag(t1b, 0, hi);
    bf1[3] = chain_frag(t1b, 1, hi);

    // ---- GEMM2: e_new = sp(t1) @ euW2 + eub2
    floatx16 ea = {};
    floatx16 eb = {};
#pragma unroll
    for (int ks = 0; ks < 5; ++ks) {
        half8 b;
        if (ks < 4) b = bf1[ks & 3]; else b = ones;
        ea = mfma32(WBv[(26 + 0 * 5 + ks) * 64 + lane], b, ea);
        eb = mfma32(WBv[(26 + 1 * 5 + ks) * 64 + lane], b, eb);
    }
    {   // store e_new: lane holds d = q + 4h + 8rg + 32mt for its edge
        _Float16* dst = (_Float16*)eT + (size_t)(e0 + e) * DIM + 4 * h;
#pragma unroll
        for (int rg = 0; rg < 4; ++rg) {
            int2 v; v.x = pkcvt(ea[4*rg+0], ea[4*rg+1]);
            v.y = pkcvt(ea[4*rg+2], ea[4*rg+3]);
            *(int2*)(dst + 8 * rg) = v;
            int2 w; w.x = pkcvt(eb[4*rg+0], eb[4*rg+1]);
            w.y = pkcvt(eb[4*rg+2], eb[4*rg+3]);
            *(int2*)(dst + 32 + 8 * rg) = w;
        }
    }

    // ---- GEMM3 (fused): t2 = nuW1_top^T@hs + W'^T@sp(t1) + b'
    floatx16 t2a = {};
    floatx16 t2b = {};
#pragma unroll
    for (int ks = 0; ks < 4; ++ks) {
        t2a = mfma32(WBv[(36 + 0 * 4 + ks) * 64 + lane], fs[ks], t2a);
        t2b = mfma32(WBv[(36 + 1 * 4 + ks) * 64 + lane], fs[ks], t2b);
    }
#pragma unroll
    for (int ks = 0; ks < 5; ++ks) {
        half8 b;
        if (ks < 4) b = bf1[ks & 3]; else b = ones;
        t2a = mfma32(WBv[(44 + 0 * 5 + ks) * 64 + lane], b, t2a);
        t2b = mfma32(WBv[(44 + 1 * 5 + ks) * 64 + lane], b, t2b);
    }
#pragma unroll
    for (int i = 0; i < 16; ++i) {
        t2a[i] = softplus_f(t2a[i]);
        t2b[i] = softplus_f(t2b[i]);
    }
    half8 bf2[4];
    bf2[0] = chain_frag(t2a, 0, hi);
    bf2[1] = chain_frag(t2a, 1, hi);
    bf2[2] = chain_frag(t2b, 0, hi);
    bf2[3] = chain_frag(t2b, 1, hi);

    // ---- GEMM4: m = sp(t2) @ nuW2 + nub2
    floatx16 ma = {};
    floatx16 mb = {};
#pragma unroll
    for (int ks = 0; ks < 5; ++ks) {
        half8 b;
        if (ks < 4) b = bf2[ks & 3]; else b = ones;
        ma = mfma32(WBv[(54 + 0 * 5 + ks) * 64 + lane], b, ma);
        mb = mfma32(WBv[(54 + 1 * 5 + ks) * 64 + lane], b, mb);
    }
    {   // store raw C-layout: slot halves = ((mt*4+rg)*64 + lane)*4 (+q)
        _Float16* base = (_Float16*)m + (size_t)blockIdx.x * 2048;
#pragma unroll
        for (int rg = 0; rg < 4; ++rg) {
            int2 v; v.x = pkcvt(ma[4*rg+0], ma[4*rg+1]);
            v.y = pkcvt(ma[4*rg+2], ma[4*rg+3]);
            *(int2*)(base + (rg * 64 + lane) * 4) = v;
            int2 w; w.x = pkcvt(mb[4*rg+0], mb[4*rg+1]);
            w.y = pkcvt(mb[4*rg+2], mb[4*rg+3]);
            *(int2*)(base + ((4 + rg) * 64 + lane) * 4) = w;
        }
    }
}

// -------------------- segment sum over raw-C-layout m.
// Value at (edge g, d): d = q + 4*(h + 2rg + 8mt); stored in 32-edge block
// g>>5 at halves ((mt*4+rg)*64 + h*32 + (g&31))*4 + q.
// Lane = dg(0..15) x ep(0..3): lane handles d=4dg..4dg+3, edge stream ep.
__global__ __launch_bounds__(256) void k_agg(
    const __half* __restrict__ m, const int* __restrict__ starts,
    __half* __restrict__ hn)
{
    const int w = threadIdx.x >> 6;
    const int lane = threadIdx.x & 63;
    const int n = blockIdx.x * 4 + w;
    const int s = starts[n], e = starts[n + 1];
    const int dg = lane & 15, ep = lane >> 4;
    const int mt = dg >> 3, rg = (dg >> 1) & 3, h = dg & 1;
    const int slotbase = ((mt * 4 + rg) * 64 + h * 32);
    float a0 = 0.f, a1 = 0.f, a2 = 0.f, a3 = 0.f;
    for (int g = s + ep; g < e; g += 4) {
        const _Float16* p = (const _Float16*)m + ((size_t)(g >> 5) * 2048)
                            + (size_t)(slotbase + (g & 31)) * 4;
        int2 v = *(const int2*)p;
        __half2 l0, l1;
        __builtin_memcpy(&l0, &v.x, 4);
        __builtin_memcpy(&l1, &v.y, 4);
        float2 f0 = __half22float2(l0), f1 = __half22float2(l1);
        a0 += f0.x; a1 += f0.y; a2 += f1.x; a3 += f1.y;
    }
    a0 += __shfl_xor(a0, 16); a1 += __shfl_xor(a1, 16);
    a2 += __shfl_xor(a2, 16); a3 += __shfl_xor(a3, 16);
    a0 += __shfl_xor(a0, 32); a1 += __shfl_xor(a1, 32);
    a2 += __shfl_xor(a2, 32); a3 += __shfl_xor(a3, 32);
    if (lane < 16) {
        int2 o; o.x = pkcvt(a0, a1); o.y = pkcvt(a2, a3);
        *(int2*)((_Float16*)hn + (size_t)n * DIM + dg * 4) = o;
    }
}

// ---------------------------------------------------------------- BN + update
__global__ __launch_bounds__(256) void k_bnstats(const __half* __restrict__ hn,
                                                 float* __restrict__ stats)
{
    const int j = threadIdx.x & 63;
    const int sub = threadIdx.x >> 6;
    const int r0 = blockIdx.x * 256;
    float s = 0.f, qq = 0.f;
    for (int i = 0; i < 64; ++i) {
        float v = (float)hn[(size_t)(r0 + i * 4 + sub) * DIM + j];
        s += v;
        qq = fmaf(v, v, qq);
    }
    __shared__ float ls[256], lq[256];
    ls[threadIdx.x] = s; lq[threadIdx.x] = qq;
    __syncthreads();
    if (threadIdx.x < 128) {
        ls[threadIdx.x] += ls[threadIdx.x + 128];
        lq[threadIdx.x] += lq[threadIdx.x + 128];
    }
    __syncthreads();
    if (threadIdx.x < 64) {
        atomicAdd(&stats[j],      ls[threadIdx.x] + ls[threadIdx.x + 64]);
        atomicAdd(&stats[64 + j], lq[threadIdx.x] + lq[threadIdx.x + 64]);
    }
}

__global__ __launch_bounds__(256) void k_hupd(
    const __half* __restrict__ hn, float* __restrict__ h,
    __half* __restrict__ h16,
    const float* __restrict__ stats, const float* __restrict__ gamma,
    const float* __restrict__ beta)
{
    const size_t idx = (size_t)blockIdx.x * 256 + threadIdx.x;
    const int j = (int)(idx & 63);
    const float inv_n = 1.0f / (float)N_NODES;
    float mu  = stats[j] * inv_n;
    float var = stats[64 + j] * inv_n - mu * mu;
    float sc  = gamma[j] * rsqrtf(var + BN_EPS);
    float v   = ((float)hn[idx] - mu) * sc + beta[j];
    float nh  = h[idx] + softplus_f(v);
    h[idx] = nh;
    h16[idx] = (__half)nh;
}

// ---------------------------------------------------------------- pool + MLP
__global__ __launch_bounds__(64) void k_pool(const float* __restrict__ h,
                                             const int* __restrict__ tsi,
                                             float* __restrict__ gr)
{
    const int g = blockIdx.x, j = threadIdx.x;
    float s = 0.f;
#pragma unroll
    for (int t = 0; t < TS; ++t) {
        int p = tsi[g * TS + t];
        s += h[(size_t)(g * P_NODES + p) * DIM + j];
    }
    gr[g * DIM + j] = s * (1.0f / TS);
}

__global__ __launch_bounds__(128) void k_pred(const float* __restrict__ gr,
    const float* __restrict__ W1, const float* __restrict__ b1,
    const float* __restrict__ W2, const float* __restrict__ b2,
    const float* __restrict__ W3, const float* __restrict__ b3,
    float* __restrict__ out)
{
    const int g = blockIdx.x, j = threadIdx.x;
    __shared__ float zin[DIM], z1[HID], red[HID];
    if (j < DIM) zin[j] = gr[g * DIM + j];
    __syncthreads();
    float a = b1[j];
    for (int k = 0; k < DIM; ++k) a = fmaf(zin[k], W1[k * HID + j], a);
    z1[j] = softplus_f(a);
    __syncthreads();
    float a2 = b2[j];
    for (int k = 0; k < HID; ++k) a2 = fmaf(z1[k], W2[k * HID + j], a2);
    red[j] = softplus_f(a2) * W3[j];
    __syncthreads();
    for (int s = 64; s > 0; s >>= 1) {
        if (j < s) red[j] += red[j + s];
        __syncthreads();
    }
    if (j == 0) out[g] = red[0] + b3[0];
}

extern "C" void kernel_launch(void* const* d_in, const int* in_sizes, int n_in,
                              void* d_out, int out_size, void* d_ws, size_t ws_size,
                              hipStream_t stream)
{
    const float* x      = (const float*)d_in[0];
    const float* eattr  = (const float*)d_in[1];
    const float* charge = (const float*)d_in[2];
    const float* chW    = (const float*)d_in[3];
    const float* chb    = (const float*)d_in[4];
    const float* atomW  = (const float*)d_in[5];
    const float* atomb  = (const float*)d_in[6];
    const float* bondW  = (const float*)d_in[7];
    const float* bondb  = (const float*)d_in[8];
    const float* nuW1   = (const float*)d_in[9];
    const float* nub1   = (const float*)d_in[10];
    const float* nuW2   = (const float*)d_in[11];
    const float* nub2   = (const float*)d_in[12];
    const float* euW1   = (const float*)d_in[13];
    const float* eub1   = (const float*)d_in[14];
    const float* euW2   = (const float*)d_in[15];
    const float* eub2   = (const float*)d_in[16];
    const float* gamma  = (const float*)d_in[17];
    const float* beta   = (const float*)d_in[18];
    const float* pW1    = (const float*)d_in[19];
    const float* pb1    = (const float*)d_in[20];
    const float* pW2    = (const float*)d_in[21];
    const float* pb2    = (const float*)d_in[22];
    const float* pW3    = (const float*)d_in[23];
    const float* pb3    = (const float*)d_in[24];
    const int*   eidx   = (const int*)d_in[25];
    const int*   batch  = (const int*)d_in[26];
    const int*   tsi    = (const int*)d_in[27];
    const int* erow = eidx;
    const int* ecol = eidx + N_EDGES;

    // workspace (~296 MB):
    // h@0 16M | hn(fp16)@16M 8M (ipos aliases first 4M) | h16@24M 8M |
    // stats@32M | gr@32M+64K | bs@32M+192K | bo@32M+196K |
    // counts@33M | starts@33M+256K | cur@33M+768K |
    // WfragB@34M 192K | Wbond@34M+256K 8K | bfu@34M+384K | WfuF32@34M+448K 48K |
    // perm@35M 4M | eT@40M 128M | m@168M 128M
    char* ws = (char*)d_ws;
    float*  h      = (float*)(ws);
    __half* hn     = (__half*)(ws + ((size_t)16 << 20));
    int*    ipos   = (int*)  (ws + ((size_t)16 << 20));   // aliases hn (safe)
    __half* h16    = (__half*)(ws + ((size_t)24 << 20));
    float*  stats  = (float*)(ws + ((size_t)32 << 20));
    float*  gr     = (float*)(ws + ((size_t)32 << 20) + (64 << 10));
    int*    bs     = (int*)  (ws + ((size_t)32 << 20) + (192 << 10));
    int*    bo     = (int*)  (ws + ((size_t)32 << 20) + (196 << 10));
    int*    counts = (int*)  (ws + ((size_t)33 << 20));
    int*    starts = (int*)  (ws + ((size_t)33 << 20) + (256 << 10));
    int*    cur    = (int*)  (ws + ((size_t)33 << 20) + (768 << 10));
    __half* WfragB = (__half*)(ws + ((size_t)34 << 20));
    __half* Wbond  = (__half*)(ws + ((size_t)34 << 20) + (256 << 10));
    float*  bfu    = (float*)(ws + ((size_t)34 << 20) + (384 << 10));
    float*  WfuF32 = (float*)(ws + ((size_t)34 << 20) + (448 << 10));
    int*    perm   = (int*)  (ws + ((size_t)35 << 20));
    __half* eT     = (__half*)(ws + ((size_t)40 << 20));
    __half* m      = (__half*)(ws + ((size_t)168 << 20));

    // ---- CSR build (edge order for ALL layers = dst-sorted via perm/ipos)
    hipMemsetAsync(counts, 0, N_NODES * sizeof(int), stream);
    k_hist<<<N_EDGES / 256, 256, 0, stream>>>(ecol, counts);
    k_blksum<<<256, 256, 0, stream>>>(counts, bs);
    k_scanb<<<1, 256, 0, stream>>>(bs, bo);
    k_scan3<<<256, 256, 0, stream>>>(counts, bo, starts);
    hipMemcpyAsync(cur, starts, N_NODES * sizeof(int),
                   hipMemcpyDeviceToDevice, stream);
    k_scatter<<<N_EDGES / 256, 256, 0, stream>>>(ecol, cur, perm, ipos);

    // ---- weight prep
    k_wfuse<<<3, 64, 0, stream>>>(euW2, nuW1, eub2, nub1, WfuF32, bfu);
    k_wprepB<<<(3 * 32768) / 256, 256, 0, stream>>>(euW1, eub1, euW2, eub2,
        nuW1, WfuF32, bfu, nuW2, nub2, WfragB);
    k_wprep_bond<<<16, 256, 0, stream>>>(bondW, Wbond);

    // ---- embeddings
    k_h0<<<N_NODES / 64, 64, 0, stream>>>(x, charge, chW, chb, atomW, atomb,
                                          batch, h, h16);
    k_e0m<<<N_EDGES / 32, 64, 0, stream>>>(eattr, Wbond, bondb, ipos, eT);

    for (int i = 0; i < NLAYER; ++i) {
        hipMemsetAsync(stats, 0, 128 * sizeof(float), stream);
        k_edge5<<<N_EDGES / 32, 64, 0, stream>>>(h16, eT,
            WfragB + (size_t)i * 32768, erow, ecol, perm, m);
        k_agg<<<N_NODES / 4, 256, 0, stream>>>(m, starts, hn);
        k_bnstats<<<N_NODES / 256, 256, 0, stream>>>(hn, stats);
        k_hupd<<<(N_NODES * DIM) / 256, 256, 0, stream>>>(hn, h, h16, stats,
            gamma + i * DIM, beta + i * DIM);
    }

    k_pool<<<N_GRAPH, 64, 0, stream>>>(h, tsi, gr);
    k_pred<<<N_GRAPH, HID, 0, stream>>>(gr, pW1, pb1, pW2, pb2, pW3, pb3, (float*)d_out);
}

// Round 6
// 1525.754 us; speedup vs baseline: 1.0167x; 1.0167x over previous
//
#include <hip/hip_runtime.h>
#include <hip/hip_bf16.h>
#include <hip/hip_fp16.h>
#include <math.h>

#define N_NODES 65536
#define N_GRAPH 256
#define P_NODES 256
#define N_EDGES 1048576
#define AF 92
#define BF 41
#define DIM 64
#define HID 128
#define NLAYER 3
#define CE 16
#define TS 4
#define BN_EPS 1e-5f
#define PSTRIDE 33    // padded edge-dim stride of LDS panel in k_e0m

typedef _Float16 half8 __attribute__((ext_vector_type(8)));
typedef float floatx4 __attribute__((ext_vector_type(4)));
typedef float floatx16 __attribute__((ext_vector_type(16)));

// fast softplus: native v_exp/v_log, abs err ~1e-7 (budget 2e-2)
__device__ __forceinline__ float softplus_f(float x) {
    return fmaxf(x, 0.0f) + __logf(1.0f + __expf(-fabsf(x)));
}

// pack two floats to 2xfp16 in an int (via documented HIP API; compiles to cvt+pack)
__device__ __forceinline__ int pkcvt(float a, float b) {
    __half2 h = __floats2half2_rn(a, b);
    int r; __builtin_memcpy(&r, &h, 4); return r;
}

__device__ __forceinline__ half8 mk8(int a, int b, int c, int d) {
    union { half8 v; int i[4]; } u;
    u.i[0] = a; u.i[1] = b; u.i[2] = c; u.i[3] = d;
    return u.v;
}

__device__ __forceinline__ floatx16 mfma32(half8 a, half8 b, floatx16 c) {
    return __builtin_amdgcn_mfma_f32_32x32x16_f16(a, b, c, 0, 0, 0);
}

// C-frag (32x32: col=lane&31=edge, row=(reg&3)+8*(reg>>2)+4*(lane>>5)) ->
// B-frag of next GEMM (col=lane&31, k=(lane>>5)*8+j) for kstep pair s_local.
// Own-half supplies 4 of the 8 k's; the other 4 come via lane^32 exchange.
__device__ __forceinline__ half8 chain_frag(const floatx16& t, int s_local, bool hi) {
    const int rA = 8 * s_local;       // reg base of row-group 2*s_local
    const int rB = rA + 4;            // reg base of row-group 2*s_local+1
    int A0 = pkcvt(t[rA + 0], t[rA + 1]);
    int A1 = pkcvt(t[rA + 2], t[rA + 3]);
    int B0 = pkcvt(t[rB + 0], t[rB + 1]);
    int B1 = pkcvt(t[rB + 2], t[rB + 3]);
    int S0 = hi ? A0 : B0, S1 = hi ? A1 : B1;   // lo sends B-group, hi sends A-group
    int R0 = __shfl_xor(S0, 32), R1 = __shfl_xor(S1, 32);
    int w0 = hi ? R0 : A0, w1 = hi ? R1 : A1;
    int w2 = hi ? B0 : R0, w3 = hi ? B1 : R1;
    return mk8(w0, w1, w2, w3);
}

// ---------------------------------------------------------------- initial h
__global__ __launch_bounds__(64) void k_h0(
    const float* __restrict__ x, const float* __restrict__ charge,
    const float* __restrict__ chW, const float* __restrict__ chb,
    const float* __restrict__ atomW, const float* __restrict__ atomb,
    const int* __restrict__ batch, float* __restrict__ h,
    __half* __restrict__ h16)
{
    const int n = blockIdx.x * 64 + threadIdx.x;
    float acc[DIM];
#pragma unroll
    for (int j = 0; j < DIM; ++j) acc[j] = atomb[j];
    const float* xr = x + (size_t)n * AF;
    for (int k2 = 0; k2 < AF; k2 += 2) {
        float2 a = *(const float2*)(xr + k2);
        {
            const float* w = atomW + (size_t)k2 * DIM;
#pragma unroll
            for (int j = 0; j < DIM; ++j) acc[j] = fmaf(w[j], a.x, acc[j]);
        }
        {
            const float* w = atomW + (size_t)(k2 + 1) * DIM;
#pragma unroll
            for (int j = 0; j < DIM; ++j) acc[j] = fmaf(w[j], a.y, acc[j]);
        }
    }
    const float cg = charge[batch[n]];
#pragma unroll
    for (int k = 0; k < CE; ++k) {
        float av = fmaf(cg, chW[k], chb[k]);
        const float* w = atomW + (size_t)(AF + k) * DIM;
#pragma unroll
        for (int j = 0; j < DIM; ++j) acc[j] = fmaf(w[j], av, acc[j]);
    }
    float* hp = h + (size_t)n * DIM;
    _Float16* hq = (_Float16*)h16 + (size_t)n * DIM;
#pragma unroll
    for (int j = 0; j < DIM; j += 4)
        *(float4*)(hp + j) = make_float4(acc[j], acc[j+1], acc[j+2], acc[j+3]);
#pragma unroll
    for (int j = 0; j < DIM; j += 8) {
        half8 hv;
#pragma unroll
        for (int u = 0; u < 8; ++u) hv[u] = (_Float16)acc[j + u];
        *(half8*)(hq + j) = hv;
    }
}

// ---------------------------------------------------------------- CSR build
__global__ __launch_bounds__(256) void k_hist(const int* __restrict__ ecol,
                                              int* __restrict__ cnt)
{
    int t = blockIdx.x * 256 + threadIdx.x;
    atomicAdd(&cnt[ecol[t]], 1);
}

__global__ __launch_bounds__(256) void k_blksum(const int* __restrict__ cnt,
                                                int* __restrict__ bs)
{
    __shared__ int red[256];
    red[threadIdx.x] = cnt[blockIdx.x * 256 + threadIdx.x];
    __syncthreads();
    for (int o = 128; o > 0; o >>= 1) {
        if (threadIdx.x < o) red[threadIdx.x] += red[threadIdx.x + o];
        __syncthreads();
    }
    if (threadIdx.x == 0) bs[blockIdx.x] = red[0];
}

__global__ __launch_bounds__(256) void k_scanb(const int* __restrict__ bs,
                                               int* __restrict__ bo)
{
    __shared__ int ps[256];
    const int t = threadIdx.x;
    int v = bs[t];
    ps[t] = v;
    __syncthreads();
    for (int off = 1; off < 256; off <<= 1) {
        int u = (t >= off) ? ps[t - off] : 0;
        __syncthreads();
        ps[t] += u;
        __syncthreads();
    }
    bo[t] = ps[t] - v;   // exclusive
}

__global__ __launch_bounds__(256) void k_scan3(const int* __restrict__ cnt,
                                               const int* __restrict__ bo,
                                               int* __restrict__ starts)
{
    __shared__ int ps[256];
    const int b = blockIdx.x, t = threadIdx.x;
    int v = cnt[b * 256 + t];
    ps[t] = v;
    __syncthreads();
    for (int off = 1; off < 256; off <<= 1) {
        int u = (t >= off) ? ps[t - off] : 0;
        __syncthreads();
        ps[t] += u;
        __syncthreads();
    }
    starts[b * 256 + t] = bo[b] + ps[t] - v;
    if (b == 255 && t == 255) starts[N_NODES] = bo[255] + ps[255];
}

__global__ __launch_bounds__(256) void k_scatter(const int* __restrict__ ecol,
                                                 int* __restrict__ cur,
                                                 int* __restrict__ perm,
                                                 int* __restrict__ ipos)
{
    int t = blockIdx.x * 256 + threadIdx.x;
    int pos = atomicAdd(&cur[ecol[t]], 1);
    perm[pos] = t;
    ipos[t] = pos;
}

// ------------- bondW [41x64] -> fp16 B-frag (16x16x32 layout) for k_e0m
__global__ __launch_bounds__(256) void k_wprep_bond(
    const float* __restrict__ bondW, __half* __restrict__ out)
{
    const int idx = blockIdx.x * 256 + threadIdx.x;   // 4096 threads
    int j    = idx & 7;
    int lane = (idx >> 3) & 63;
    int f    = idx >> 9;
    int ntile = f & 3;
    int kIter = f >> 2;
    int k = kIter * 32 + ((lane >> 4) & 3) * 8 + j;
    int n = ntile * 16 + (lane & 15);
    out[idx] = (k < BF) ? __float2half(bondW[k * 64 + n]) : __float2half(0.0f);
}

// fused weight: W' = euW2 @ nuW1_bot  [64x64], b' = eub2 @ nuW1_bot + nub1.
__global__ __launch_bounds__(64) void k_wfuse(
    const float* __restrict__ euW2, const float* __restrict__ nuW1,
    const float* __restrict__ eub2, const float* __restrict__ nub1,
    float* __restrict__ WfuF32, float* __restrict__ bfu)
{
    const int L = blockIdx.x, j = threadIdx.x;
    const float* W2  = euW2 + (size_t)L * DIM * DIM;             // [k][l]
    const float* N1b = nuW1 + (size_t)L * 128 * DIM + 64 * DIM;  // [l][j]
    float acc[64];
#pragma unroll
    for (int k = 0; k < 64; ++k) acc[k] = 0.f;
    for (int l = 0; l < 64; ++l) {
        float nv = N1b[l * 64 + j];
#pragma unroll
        for (int k = 0; k < 64; ++k) acc[k] = fmaf(W2[k * 64 + l], nv, acc[k]);
    }
    float* outW = WfuF32 + (size_t)L * 4096;
    for (int k = 0; k < 64; ++k) outW[k * 64 + j] = acc[k];
    float b = nub1[L * 64 + j];
    for (int l = 0; l < 64; ++l) b = fmaf(eub2[L * 64 + l], N1b[l * 64 + j], b);
    bfu[L * 64 + j] = b;
}

// -------- A-frag prepack for k_edge5 (32x32x16: row=l&31, k=(l>>5)*8+j).
// Per layer, 64 frags of 1KB (64 lanes x half8):
//  F  0..25 : G1  euW1^T (+eub1 at k=192)   mt*13+ks, K=13 ksteps
//  F 26..35 : G2  euW2^T (+eub2 at k=64)    26+mt*5+ks
//  F 36..43 : G3a nuW1_top^T (no bias)      36+mt*4+ks
//  F 44..53 : G3b W'^T (+b' at k=64)        44+mt*5+ks
//  F 54..63 : G4  nuW2^T (+nub2 at k=64)    54+mt*5+ks
__global__ __launch_bounds__(256) void k_wprepB(
    const float* __restrict__ euW1, const float* __restrict__ eub1,
    const float* __restrict__ euW2, const float* __restrict__ eub2,
    const float* __restrict__ nuW1, const float* __restrict__ WfuF32,
    const float* __restrict__ bfu,  const float* __restrict__ nuW2,
    const float* __restrict__ nub2, __half* __restrict__ out)
{
    const int idx = blockIdx.x * 256 + threadIdx.x;   // 3*32768 threads
    const int L = idx >> 15;
    const int off = idx & 32767;
    const int F = off >> 9;
    const int l = (off >> 3) & 63;
    const int j = off & 7;
    const int k_oct = ((l >> 5) << 3) + j;
    const int row = (l & 31);
    float val;
    if (F < 26) {
        int mt = F / 13, ks = F - mt * 13;
        int k = ks * 16 + k_oct, r = mt * 32 + row;
        val = (k < 192) ? euW1[(size_t)L * 192 * DIM + k * 64 + r]
            : (k == 192 ? eub1[L * 64 + r] : 0.f);
    } else if (F < 36) {
        int f = F - 26; int mt = f / 5, ks = f - mt * 5;
        int k = ks * 16 + k_oct, r = mt * 32 + row;
        val = (k < 64) ? euW2[(size_t)L * 4096 + k * 64 + r]
            : (k == 64 ? eub2[L * 64 + r] : 0.f);
    } else if (F < 44) {
        int f = F - 36; int mt = f / 4, ks = f - mt * 4;
        int k = ks * 16 + k_oct, r = mt * 32 + row;
        val = nuW1[(size_t)L * 8192 + k * 64 + r];
    } else if (F < 54) {
        int f = F - 44; int mt = f / 5, ks = f - mt * 5;
        int k = ks * 16 + k_oct, r = mt * 32 + row;
        val = (k < 64) ? WfuF32[(size_t)L * 4096 + k * 64 + r]
            : (k == 64 ? bfu[L * 64 + r] : 0.f);
    } else {
        int f = F - 54; int mt = f / 5, ks = f - mt * 5;
        int k = ks * 16 + k_oct, r = mt * 32 + row;
        val = (k < 64) ? nuW2[(size_t)L * 4096 + k * 64 + r]
            : (k == 64 ? nub2[L * 64 + r] : 0.f);
    }
    out[idx] = __float2half(val);
}

// ---------------- 16x16x32 helpers (used by k_e0m only)
__device__ __forceinline__ void init_acc(floatx4 acc[2][4],
                                         const float* __restrict__ b, int mrow)
{
#pragma unroll
    for (int n = 0; n < 4; ++n) {
        float bv = b[n * 16 + mrow];
        floatx4 f = {bv, bv, bv, bv};
        acc[0][n] = f;
        acc[1][n] = f;
    }
}

__device__ __forceinline__ void gemm_panel(floatx4 acc[2][4],
                                           const _Float16* __restrict__ P,
                                           const __half* __restrict__ Wf,
                                           int fragBase, int quad,
                                           int mrow, int lane)
{
    const _Float16* Wh = (const _Float16*)Wf;
#pragma unroll
    for (int ki = 0; ki < 2; ++ki) {
        const _Float16* pa = P + (size_t)(((ki * 4 + quad) * PSTRIDE + mrow) * 8);
        half8 a0 = *(const half8*)pa;
        half8 a1 = *(const half8*)(pa + 16 * 8);
#pragma unroll
        for (int n = 0; n < 4; ++n) {
            half8 b = *(const half8*)(Wh +
                ((size_t)(fragBase + ki * 4 + n) * 64 + lane) * 8);
            acc[0][n] = __builtin_amdgcn_mfma_f32_16x16x32_f16(a0, b, acc[0][n], 0, 0, 0);
            acc[1][n] = __builtin_amdgcn_mfma_f32_16x16x32_f16(a1, b, acc[1][n], 0, 0, 0);
        }
    }
}

__device__ __forceinline__ void cstore_panel(const floatx4 acc[2][4],
                                             _Float16* __restrict__ P,
                                             int quad, int mrow, bool sp)
{
#pragma unroll
    for (int t = 0; t < 2; ++t)
#pragma unroll
        for (int n = 0; n < 4; ++n)
#pragma unroll
            for (int r = 0; r < 4; ++r) {
                int edge = t * 16 + quad * 4 + r;
                int d = n * 16 + mrow;
                float v = acc[t][n][r];
                if (sp) v = softplus_f(v);
                P[((d >> 3) * PSTRIDE + edge) * 8 + (d & 7)] = (_Float16)v;
            }
}

// ---- initial e as MFMA GEMM: eT[slot] = eattr[E,41] @ bondW[41,64] + bondb.
__device__ __forceinline__ void stage_e2(_Float16* __restrict__ P,
                                         int id2, float2 v)
{
    int idx = id2 * 2;
    int e = (idx * 51151) >> 21;          // floor(idx/41), exact for idx<2^15
    int k = idx - e * 41;
    P[((k >> 3) * PSTRIDE + e) * 8 + (k & 7)] = (_Float16)v.x;
    idx++;
    e = (idx * 51151) >> 21;
    k = idx - e * 41;
    P[((k >> 3) * PSTRIDE + e) * 8 + (k & 7)] = (_Float16)v.y;
}

__global__ __launch_bounds__(64) void k_e0m(
    const float* __restrict__ eattr, const __half* __restrict__ Wb,
    const float* __restrict__ bondb, const int* __restrict__ ipos,
    __half* __restrict__ eT)
{
    __shared__ __align__(16) _Float16 P0[8 * PSTRIDE * 8];
    __shared__ int slot[32];
    const int lane = threadIdx.x;
    const int quad = lane >> 4;
    const int mrow = lane & 15;
    const int e0   = blockIdx.x * 32;

    if (lane < 32) slot[lane] = ipos[e0 + lane];

    {
        half8 z = {};
#pragma unroll
        for (int i = 0; i < 4; ++i) ((half8*)P0)[i * 64 + lane] = z;
        if (lane < 8) ((half8*)P0)[256 + lane] = z;
    }
    __syncthreads();

    const float* src = eattr + (size_t)e0 * BF;
#pragma unroll
    for (int i = 0; i < 10; ++i) {
        const int id2 = i * 64 + lane;
        float2 v = *(const float2*)(src + id2 * 2);
        stage_e2(P0, id2, v);
    }
    if (lane < 16) {
        const int id2 = 640 + lane;
        float2 v = *(const float2*)(src + id2 * 2);
        stage_e2(P0, id2, v);
    }
    __syncthreads();

    floatx4 acc[2][4];
    init_acc(acc, bondb, mrow);
    gemm_panel(acc, P0, Wb, 0, quad, mrow, lane);
    __syncthreads();
    cstore_panel(acc, P0, quad, mrow, false);
    __syncthreads();

#pragma unroll
    for (int i = 0; i < 4; ++i) {
        int idx = i * 64 + lane;
        int eL = idx >> 3;
        int c  = idx & 7;
        half8 v = *(const half8*)&P0[(c * PSTRIDE + eL) * 8];
        *(half8*)((_Float16*)eT + (size_t)slot[eL] * DIM + c * 8) = v;
    }
}

// ---------------------------------------------------------------- edge MLP
// 4 independent waves / block (256 threads, 128 edges): single-wave workgroups
// cap at ~16 wg/CU (= 50% occupancy); 4-wave workgroups reach 8 wg x 4 waves
// = 32 waves/CU. Each wave owns 32 edges; swapped-operand 32x32x16 MFMA chain
// stays fully in registers (no LDS, no barriers).
__global__ __launch_bounds__(256) void k_edge5(
    const __half* __restrict__ h16, __half* __restrict__ eT,
    const __half* __restrict__ WB,
    const int* __restrict__ erow, const int* __restrict__ ecol,
    const int* __restrict__ perm, __half* __restrict__ m)
{
    const int lane = threadIdx.x & 63;
    const int wid  = threadIdx.x >> 6;
    const int grp  = blockIdx.x * 4 + wid;    // global 32-edge group id
    const int e = lane & 31;
    const bool hi = lane >= 32;
    const int h = hi ? 1 : 0;
    const int e0 = grp * 32;
    const int ed = perm[e0 + e];
    const int rs = erow[ed], cs = ecol[ed];

    const half8* WBv = (const half8*)WB;

    half8 fs[4], fd[4], fe[4];
    {
        const _Float16* ps = (const _Float16*)h16 + (size_t)rs * DIM + h * 8;
        const _Float16* pd = (const _Float16*)h16 + (size_t)cs * DIM + h * 8;
        const _Float16* pe = (const _Float16*)eT  + (size_t)(e0 + e) * DIM + h * 8;
#pragma unroll
        for (int s = 0; s < 4; ++s) {
            fs[s] = *(const half8*)(ps + 16 * s);
            fd[s] = *(const half8*)(pd + 16 * s);
            fe[s] = *(const half8*)(pe + 16 * s);
        }
    }
    half8 ones = {};
    if (!hi) ones[0] = (_Float16)1.0f;   // k_local==0 row only

    // ---- GEMM1: t1^T = euW1^T @ [hs|hd|e]^T (+eub1)
    floatx16 t1a = {};
    floatx16 t1b = {};
#pragma unroll
    for (int ks = 0; ks < 13; ++ks) {
        half8 b;
        if (ks < 4)       b = fs[ks & 3];
        else if (ks < 8)  b = fd[(ks - 4) & 3];
        else if (ks < 12) b = fe[(ks - 8) & 3];
        else              b = ones;
        t1a = mfma32(WBv[(0 * 13 + ks) * 64 + lane], b, t1a);
        t1b = mfma32(WBv[(1 * 13 + ks) * 64 + lane], b, t1b);
    }
#pragma unroll
    for (int i = 0; i < 16; ++i) {
        t1a[i] = softplus_f(t1a[i]);
        t1b[i] = softplus_f(t1b[i]);
    }
    half8 bf1[4];
    bf1[0] = chain_frag(t1a, 0, hi);
    bf1[1] = chain_frag(t1a, 1, hi);
    bf1[2] = chain_frag(t1b, 0, hi);
    bf1[3] = chain_frag(t1b, 1, hi);

    // ---- GEMM2: e_new = sp(t1) @ euW2 + eub2
    floatx16 ea = {};
    floatx16 eb = {};
#pragma unroll
    for (int ks = 0; ks < 5; ++ks) {
        half8 b;
        if (ks < 4) b = bf1[ks & 3]; else b = ones;
        ea = mfma32(WBv[(26 + 0 * 5 + ks) * 64 + lane], b, ea);
        eb = mfma32(WBv[(26 + 1 * 5 + ks) * 64 + lane], b, eb);
    }
    {   // store e_new: lane holds d = q + 4h + 8rg + 32mt for its edge
        _Float16* dst = (_Float16*)eT + (size_t)(e0 + e) * DIM + 4 * h;
#pragma unroll
        for (int rg = 0; rg < 4; ++rg) {
            int2 v; v.x = pkcvt(ea[4*rg+0], ea[4*rg+1]);
            v.y = pkcvt(ea[4*rg+2], ea[4*rg+3]);
            *(int2*)(dst + 8 * rg) = v;
            int2 w; w.x = pkcvt(eb[4*rg+0], eb[4*rg+1]);
            w.y = pkcvt(eb[4*rg+2], eb[4*rg+3]);
            *(int2*)(dst + 32 + 8 * rg) = w;
        }
    }

    // ---- GEMM3 (fused): t2 = nuW1_top^T@hs + W'^T@sp(t1) + b'
    floatx16 t2a = {};
    floatx16 t2b = {};
#pragma unroll
    for (int ks = 0; ks < 4; ++ks) {
        t2a = mfma32(WBv[(36 + 0 * 4 + ks) * 64 + lane], fs[ks], t2a);
        t2b = mfma32(WBv[(36 + 1 * 4 + ks) * 64 + lane], fs[ks], t2b);
    }
#pragma unroll
    for (int ks = 0; ks < 5; ++ks) {
        half8 b;
        if (ks < 4) b = bf1[ks & 3]; else b = ones;
        t2a = mfma32(WBv[(44 + 0 * 5 + ks) * 64 + lane], b, t2a);
        t2b = mfma32(WBv[(44 + 1 * 5 + ks) * 64 + lane], b, t2b);
    }
#pragma unroll
    for (int i = 0; i < 16; ++i) {
        t2a[i] = softplus_f(t2a[i]);
        t2b[i] = softplus_f(t2b[i]);
    }
    half8 bf2[4];
    bf2[0] = chain_frag(t2a, 0, hi);
    bf2[1] = chain_frag(t2a, 1, hi);
    bf2[2] = chain_frag(t2b, 0, hi);
    bf2[3] = chain_frag(t2b, 1, hi);

    // ---- GEMM4: m = sp(t2) @ nuW2 + nub2
    floatx16 ma = {};
    floatx16 mb = {};
#pragma unroll
    for (int ks = 0; ks < 5; ++ks) {
        half8 b;
        if (ks < 4) b = bf2[ks & 3]; else b = ones;
        ma = mfma32(WBv[(54 + 0 * 5 + ks) * 64 + lane], b, ma);
        mb = mfma32(WBv[(54 + 1 * 5 + ks) * 64 + lane], b, mb);
    }
    {   // store raw C-layout: slot halves = ((mt*4+rg)*64 + lane)*4 (+q)
        _Float16* base = (_Float16*)m + (size_t)grp * 2048;
#pragma unroll
        for (int rg = 0; rg < 4; ++rg) {
            int2 v; v.x = pkcvt(ma[4*rg+0], ma[4*rg+1]);
            v.y = pkcvt(ma[4*rg+2], ma[4*rg+3]);
            *(int2*)(base + (rg * 64 + lane) * 4) = v;
            int2 w; w.x = pkcvt(mb[4*rg+0], mb[4*rg+1]);
            w.y = pkcvt(mb[4*rg+2], mb[4*rg+3]);
            *(int2*)(base + ((4 + rg) * 64 + lane) * 4) = w;
        }
    }
}

// -------------------- segment sum over raw-C-layout m.
// Value at (edge g, d): d = q + 4*(h + 2rg + 8mt); stored in 32-edge block
// g>>5 at halves ((mt*4+rg)*64 + h*32 + (g&31))*4 + q.
// Lane = dg(0..15) x ep(0..3): lane handles d=4dg..4dg+3, edge stream ep.
__global__ __launch_bounds__(256) void k_agg(
    const __half* __restrict__ m, const int* __restrict__ starts,
    __half* __restrict__ hn)
{
    const int w = threadIdx.x >> 6;
    const int lane = threadIdx.x & 63;
    const int n = blockIdx.x * 4 + w;
    const int s = starts[n], e = starts[n + 1];
    const int dg = lane & 15, ep = lane >> 4;
    const int mt = dg >> 3, rg = (dg >> 1) & 3, h = dg & 1;
    const int slotbase = ((mt * 4 + rg) * 64 + h * 32);
    float a0 = 0.f, a1 = 0.f, a2 = 0.f, a3 = 0.f;
    for (int g = s + ep; g < e; g += 4) {
        const _Float16* p = (const _Float16*)m + ((size_t)(g >> 5) * 2048)
                            + (size_t)(slotbase + (g & 31)) * 4;
        int2 v = *(const int2*)p;
        __half2 l0, l1;
        __builtin_memcpy(&l0, &v.x, 4);
        __builtin_memcpy(&l1, &v.y, 4);
        float2 f0 = __half22float2(l0), f1 = __half22float2(l1);
        a0 += f0.x; a1 += f0.y; a2 += f1.x; a3 += f1.y;
    }
    a0 += __shfl_xor(a0, 16); a1 += __shfl_xor(a1, 16);
    a2 += __shfl_xor(a2, 16); a3 += __shfl_xor(a3, 16);
    a0 += __shfl_xor(a0, 32); a1 += __shfl_xor(a1, 32);
    a2 += __shfl_xor(a2, 32); a3 += __shfl_xor(a3, 32);
    if (lane < 16) {
        int2 o; o.x = pkcvt(a0, a1); o.y = pkcvt(a2, a3);
        *(int2*)((_Float16*)hn + (size_t)n * DIM + dg * 4) = o;
    }
}

// ---------------------------------------------------------------- BN + update
__global__ __launch_bounds__(256) void k_bnstats(const __half* __restrict__ hn,
                                                 float* __restrict__ stats)
{
    const int j = threadIdx.x & 63;
    const int sub = threadIdx.x >> 6;
    const int r0 = blockIdx.x * 256;
    float s = 0.f, qq = 0.f;
    for (int i = 0; i < 64; ++i) {
        float v = (float)hn[(size_t)(r0 + i * 4 + sub) * DIM + j];
        s += v;
        qq = fmaf(v, v, qq);
    }
    __shared__ float ls[256], lq[256];
    ls[threadIdx.x] = s; lq[threadIdx.x] = qq;
    __syncthreads();
    if (threadIdx.x < 128) {
        ls[threadIdx.x] += ls[threadIdx.x + 128];
        lq[threadIdx.x] += lq[threadIdx.x + 128];
    }
    __syncthreads();
    if (threadIdx.x < 64) {
        atomicAdd(&stats[j],      ls[threadIdx.x] + ls[threadIdx.x + 64]);
        atomicAdd(&stats[64 + j], lq[threadIdx.x] + lq[threadIdx.x + 64]);
    }
}

__global__ __launch_bounds__(256) void k_hupd(
    const __half* __restrict__ hn, float* __restrict__ h,
    __half* __restrict__ h16,
    const float* __restrict__ stats, const float* __restrict__ gamma,
    const float* __restrict__ beta)
{
    const size_t idx = (size_t)blockIdx.x * 256 + threadIdx.x;
    const int j = (int)(idx & 63);
    const float inv_n = 1.0f / (float)N_NODES;
    float mu  = stats[j] * inv_n;
    float var = stats[64 + j] * inv_n - mu * mu;
    float sc  = gamma[j] * rsqrtf(var + BN_EPS);
    float v   = ((float)hn[idx] - mu) * sc + beta[j];
    float nh  = h[idx] + softplus_f(v);
    h[idx] = nh;
    h16[idx] = (__half)nh;
}

// ---------------------------------------------------------------- pool + MLP
__global__ __launch_bounds__(64) void k_pool(const float* __restrict__ h,
                                             const int* __restrict__ tsi,
                                             float* __restrict__ gr)
{
    const int g = blockIdx.x, j = threadIdx.x;
    float s = 0.f;
#pragma unroll
    for (int t = 0; t < TS; ++t) {
        int p = tsi[g * TS + t];
        s += h[(size_t)(g * P_NODES + p) * DIM + j];
    }
    gr[g * DIM + j] = s * (1.0f / TS);
}

__global__ __launch_bounds__(128) void k_pred(const float* __restrict__ gr,
    const float* __restrict__ W1, const float* __restrict__ b1,
    const float* __restrict__ W2, const float* __restrict__ b2,
    const float* __restrict__ W3, const float* __restrict__ b3,
    float* __restrict__ out)
{
    const int g = blockIdx.x, j = threadIdx.x;
    __shared__ float zin[DIM], z1[HID], red[HID];
    if (j < DIM) zin[j] = gr[g * DIM + j];
    __syncthreads();
    float a = b1[j];
    for (int k = 0; k < DIM; ++k) a = fmaf(zin[k], W1[k * HID + j], a);
    z1[j] = softplus_f(a);
    __syncthreads();
    float a2 = b2[j];
    for (int k = 0; k < HID; ++k) a2 = fmaf(z1[k], W2[k * HID + j], a2);
    red[j] = softplus_f(a2) * W3[j];
    __syncthreads();
    for (int s = 64; s > 0; s >>= 1) {
        if (j < s) red[j] += red[j + s];
        __syncthreads();
    }
    if (j == 0) out[g] = red[0] + b3[0];
}

extern "C" void kernel_launch(void* const* d_in, const int* in_sizes, int n_in,
                              void* d_out, int out_size, void* d_ws, size_t ws_size,
                              hipStream_t stream)
{
    const float* x      = (const float*)d_in[0];
    const float* eattr  = (const float*)d_in[1];
    const float* charge = (const float*)d_in[2];
    const float* chW    = (const float*)d_in[3];
    const float* chb    = (const float*)d_in[4];
    const float* atomW  = (const float*)d_in[5];
    const float* atomb  = (const float*)d_in[6];
    const float* bondW  = (const float*)d_in[7];
    const float* bondb  = (const float*)d_in[8];
    const float* nuW1   = (const float*)d_in[9];
    const float* nub1   = (const float*)d_in[10];
    const float* nuW2   = (const float*)d_in[11];
    const float* nub2   = (const float*)d_in[12];
    const float* euW1   = (const float*)d_in[13];
    const float* eub1   = (const float*)d_in[14];
    const float* euW2   = (const float*)d_in[15];
    const float* eub2   = (const float*)d_in[16];
    const float* gamma  = (const float*)d_in[17];
    const float* beta   = (const float*)d_in[18];
    const float* pW1    = (const float*)d_in[19];
    const float* pb1    = (const float*)d_in[20];
    const float* pW2    = (const float*)d_in[21];
    const float* pb2    = (const float*)d_in[22];
    const float* pW3    = (const float*)d_in[23];
    const float* pb3    = (const float*)d_in[24];
    const int*   eidx   = (const int*)d_in[25];
    const int*   batch  = (const int*)d_in[26];
    const int*   tsi    = (const int*)d_in[27];
    const int* erow = eidx;
    const int* ecol = eidx + N_EDGES;

    // workspace (~296 MB):
    // h@0 16M | hn(fp16)@16M 8M (ipos aliases first 4M) | h16@24M 8M |
    // stats@32M | gr@32M+64K | bs@32M+192K | bo@32M+196K |
    // counts@33M | starts@33M+256K | cur@33M+768K |
    // WfragB@34M 192K | Wbond@34M+256K 8K | bfu@34M+384K | WfuF32@34M+448K 48K |
    // perm@35M 4M | eT@40M 128M | m@168M 128M
    char* ws = (char*)d_ws;
    float*  h      = (float*)(ws);
    __half* hn     = (__half*)(ws + ((size_t)16 << 20));
    int*    ipos   = (int*)  (ws + ((size_t)16 << 20));   // aliases hn (safe)
    __half* h16    = (__half*)(ws + ((size_t)24 << 20));
    float*  stats  = (float*)(ws + ((size_t)32 << 20));
    float*  gr     = (float*)(ws + ((size_t)32 << 20) + (64 << 10));
    int*    bs     = (int*)  (ws + ((size_t)32 << 20) + (192 << 10));
    int*    bo     = (int*)  (ws + ((size_t)32 << 20) + (196 << 10));
    int*    counts = (int*)  (ws + ((size_t)33 << 20));
    int*    starts = (int*)  (ws + ((size_t)33 << 20) + (256 << 10));
    int*    cur    = (int*)  (ws + ((size_t)33 << 20) + (768 << 10));
    __half* WfragB = (__half*)(ws + ((size_t)34 << 20));
    __half* Wbond  = (__half*)(ws + ((size_t)34 << 20) + (256 << 10));
    float*  bfu    = (float*)(ws + ((size_t)34 << 20) + (384 << 10));
    float*  WfuF32 = (float*)(ws + ((size_t)34 << 20) + (448 << 10));
    int*    perm   = (int*)  (ws + ((size_t)35 << 20));
    __half* eT     = (__half*)(ws + ((size_t)40 << 20));
    __half* m      = (__half*)(ws + ((size_t)168 << 20));

    // ---- CSR build (edge order for ALL layers = dst-sorted via perm/ipos)
    hipMemsetAsync(counts, 0, N_NODES * sizeof(int), stream);
    k_hist<<<N_EDGES / 256, 256, 0, stream>>>(ecol, counts);
    k_blksum<<<256, 256, 0, stream>>>(counts, bs);
    k_scanb<<<1, 256, 0, stream>>>(bs, bo);
    k_scan3<<<256, 256, 0, stream>>>(counts, bo, starts);
    hipMemcpyAsync(cur, starts, N_NODES * sizeof(int),
                   hipMemcpyDeviceToDevice, stream);
    k_scatter<<<N_EDGES / 256, 256, 0, stream>>>(ecol, cur, perm, ipos);

    // ---- weight prep
    k_wfuse<<<3, 64, 0, stream>>>(euW2, nuW1, eub2, nub1, WfuF32, bfu);
    k_wprepB<<<(3 * 32768) / 256, 256, 0, stream>>>(euW1, eub1, euW2, eub2,
        nuW1, WfuF32, bfu, nuW2, nub2, WfragB);
    k_wprep_bond<<<16, 256, 0, stream>>>(bondW, Wbond);

    // ---- embeddings
    k_h0<<<N_NODES / 64, 64, 0, stream>>>(x, charge, chW, chb, atomW, atomb,
                                          batch, h, h16);
    k_e0m<<<N_EDGES / 32, 64, 0, stream>>>(eattr, Wbond, bondb, ipos, eT);

    for (int i = 0; i < NLAYER; ++i) {
        hipMemsetAsync(stats, 0, 128 * sizeof(float), stream);
        k_edge5<<<N_EDGES / 128, 256, 0, stream>>>(h16, eT,
            WfragB + (size_t)i * 32768, erow, ecol, perm, m);
        k_agg<<<N_NODES / 4, 256, 0, stream>>>(m, starts, hn);
        k_bnstats<<<N_NODES / 256, 256, 0, stream>>>(hn, stats);
        k_hupd<<<(N_NODES * DIM) / 256, 256, 0, stream>>>(hn, h, h16, stats,
            gamma + i * DIM, beta + i * DIM);
    }

    k_pool<<<N_GRAPH, 64, 0, stream>>>(h, tsi, gr);
    k_pred<<<N_GRAPH, HID, 0, stream>>>(gr, pW1, pb1, pW2, pb2, pW3, pb3, (float*)d_out);
}